// Round 23
// baseline (114.637 us; speedup 1.0000x reference)
//
#include <hip/hip_runtime.h>
#include <hip/hip_bf16.h>
#include <cstdint>
#include <cmath>

#define SEQ 2048
#define NH 16
#define DM 1024
#define BATCH 2

typedef short bf16x8 __attribute__((ext_vector_type(8)));
typedef float f32x4 __attribute__((ext_vector_type(4)));
typedef const void __attribute__((address_space(1)))* gas_t;
typedef void __attribute__((address_space(3)))* las_t;

#if __has_builtin(__builtin_amdgcn_exp2f)
#define EXP2(x) __builtin_amdgcn_exp2f(x)
#else
#define EXP2(x) __expf((x) * 0.6931471805599453f)
#endif

// Q prescale: (1/sqrt(64)) * log2(e) so scores are already in log2 domain
#define QSCALE 0.18033688011112042f

#define SBAR() asm volatile("s_barrier" ::: "memory")

static __device__ __forceinline__ unsigned short f2bf(float f) {
    union { __hip_bfloat16 h; unsigned short u; } cv;
    cv.h = __float2bfloat16(f);
    return cv.u;
}
static __device__ __forceinline__ float bf2f(unsigned short u) {
    union { unsigned short u; __hip_bfloat16 h; } cv;
    cv.u = u;
    return __bfloat162float(cv.h);
}

static __device__ __forceinline__ void gload_lds16(const void* g, void* l) {
    __builtin_amdgcn_global_load_lds(
        reinterpret_cast<gas_t>(reinterpret_cast<uintptr_t>(g)),
        reinterpret_cast<las_t>(reinterpret_cast<uintptr_t>(l)),
        16, 0, 0);
}

// ---------------- fp32 -> bf16 convert + RoPE table, one launch ----------
__global__ __launch_bounds__(256) void cvt_all(
    const float* __restrict__ x,  const float* __restrict__ wq,
    const float* __restrict__ wk, const float* __restrict__ wv,
    const float* __restrict__ wo, const int* __restrict__ pos,
    unsigned short* __restrict__ xb, unsigned short* __restrict__ wqkv,
    unsigned short* __restrict__ wob, float2* __restrict__ tab) {
    int blk = blockIdx.x;
    if (blk >= 8192) {                       // RoPE cos/sin table
        int idx = (blk - 8192) * 256 + threadIdx.x;   // s*32 + i
        int s = idx >> 5, i = idx & 31;
        float fpos = (float)pos[s];
        float freq = exp2f(-(float)i * (13.287712379549449f / 32.0f));
        float ang = fpos * freq, sn, cs;
        sincosf(ang, &sn, &cs);
        tab[idx] = make_float2(cs, sn);
        return;
    }
    const float* src; unsigned short* dst; int base;
    if (blk < 4096)      { src = x;  dst = xb;              base = blk; }
    else if (blk < 5120) { src = wq; dst = wqkv;            base = blk - 4096; }
    else if (blk < 6144) { src = wk; dst = wqkv + 1048576;  base = blk - 5120; }
    else if (blk < 7168) { src = wv; dst = wqkv + 2097152;  base = blk - 6144; }
    else                 { src = wo; dst = wob;             base = blk - 7168; }
    int i = base * 256 + threadIdx.x;
    float4 v = reinterpret_cast<const float4*>(src)[i];
    ushort4 o;
    o.x = f2bf(v.x); o.y = f2bf(v.y); o.z = f2bf(v.z); o.w = f2bf(v.w);
    reinterpret_cast<ushort4*>(dst)[i] = o;
}

// ---------------- 128x128 bf16 GEMM (out-proj): C = A * B^T ----------------
template<int OUT_BF16>
__global__ __launch_bounds__(256) void gemm_bt(
    const unsigned short* __restrict__ A,
    const unsigned short* __restrict__ B,
    void* __restrict__ C, int M, int N, int K) {
    __shared__ unsigned short As[128 * 32];
    __shared__ unsigned short Bs[128 * 32];
    const int tid = threadIdx.x;
    const int lane = tid & 63, wid = tid >> 6;
    const int wr = wid >> 1, wc = wid & 1;
    const int ln15 = lane & 15, kq = lane >> 4;
    const int bm = blockIdx.y, bn = blockIdx.x;

    f32x4 acc[4][4] = {};
    const int nk = K >> 5;
    for (int kt = 0; kt < nk; ++kt) {
        #pragma unroll
        for (int i = 0; i < 2; ++i) {
            int c = i * 256 + tid;
            int row = c >> 2, k8 = (c & 3) << 3;
            size_t gofsA = (size_t)(bm * 128 + row) * K + kt * 32 + k8;
            size_t gofsB = (size_t)(bn * 128 + row) * K + kt * 32 + k8;
            unsigned ldsoff_ = (unsigned)(i * 256 + wid * 64) * 16;  // wave-uniform
            gload_lds16(A + gofsA, (char*)As + ldsoff_);
            gload_lds16(B + gofsB, (char*)Bs + ldsoff_);
        }
        __syncthreads();
        bf16x8 af[4], bf[4];
        #pragma unroll
        for (int m = 0; m < 4; ++m)
            af[m] = *reinterpret_cast<const bf16x8*>(&As[(wr * 64 + m * 16 + ln15) * 32 + kq * 8]);
        #pragma unroll
        for (int n = 0; n < 4; ++n)
            bf[n] = *reinterpret_cast<const bf16x8*>(&Bs[(wc * 64 + n * 16 + ln15) * 32 + kq * 8]);
        #pragma unroll
        for (int m = 0; m < 4; ++m)
            #pragma unroll
            for (int n = 0; n < 4; ++n)
                acc[m][n] = __builtin_amdgcn_mfma_f32_16x16x32_bf16(af[m], bf[n], acc[m][n], 0, 0, 0);
        __syncthreads();
    }
    #pragma unroll
    for (int m = 0; m < 4; ++m) {
        #pragma unroll
        for (int n = 0; n < 4; ++n) {
            int col = bn * 128 + wc * 64 + n * 16 + ln15;
            #pragma unroll
            for (int j = 0; j < 4; ++j) {
                int row = bm * 128 + wr * 64 + m * 16 + kq * 4 + j;
                if constexpr (OUT_BF16 != 0)
                    ((unsigned short*)C)[(size_t)row * N + col] = f2bf(acc[m][n][j]);
                else
                    ((float*)C)[(size_t)row * N + col] = acc[m][n][j];
            }
        }
    }
}

// ---------------- 256x256 bf16 GEMM (qkv proj), 8-phase + fused epilogue -----
// r22 + change: Q/K blocks ALSO bounce through dead As/Bs LDS (RoPE applied
// in registers, natural [row][col] layout, 4-aligned XOR swizzle) so their
// global stores are fully coalesced 256B/thread streams (were 32B segments).
__global__ __launch_bounds__(512) void gemm256_bt(
    const unsigned short* __restrict__ A,
    const unsigned short* __restrict__ B,
    unsigned short* __restrict__ Qh, unsigned short* __restrict__ Kh,
    unsigned short* __restrict__ Vtr, const float2* __restrict__ tab, int K) {
    __shared__ unsigned short As[2][256 * 64];
    __shared__ unsigned short Bs[2][256 * 64];
    const int tid = threadIdx.x;
    const int lane = tid & 63, wid = tid >> 6;
    const int wm = wid >> 2, wn = wid & 3;          // 2 x 4 waves
    const int ln15 = lane & 15, g = lane >> 4;
    const int bm = blockIdx.y, bn = blockIdx.x;

    const unsigned short* aSrc[4];
    const unsigned short* bSrc[4];
    #pragma unroll
    for (int p = 0; p < 4; ++p) {
        int c = tid + (p << 9);
        int row = c >> 3, slot = c & 7;
        aSrc[p] = A + (size_t)(bm * 256 + row) * K + ((slot ^ (row & 7)) << 3);
        bSrc[p] = B + (size_t)(bn * 256 + row) * K + ((slot ^ (row & 7)) << 3);
    }
    auto stageA = [&](int kt, int h) {   // one half-tile = 2 gload_lds / thread
        #pragma unroll
        for (int p = 2 * h; p < 2 * h + 2; ++p) {
            unsigned dst = (unsigned)(tid + (p << 9)) << 4;
            gload_lds16(aSrc[p] + kt * 64, (char*)As[kt & 1] + dst);
        }
    };
    auto stageB = [&](int kt, int h) {
        #pragma unroll
        for (int p = 2 * h; p < 2 * h + 2; ++p) {
            unsigned dst = (unsigned)(tid + (p << 9)) << 4;
            gload_lds16(bSrc[p] + kt * 64, (char*)Bs[kt & 1] + dst);
        }
    };

    const unsigned ps0 = (unsigned)((g ^ (ln15 & 7)) << 4);
    const unsigned ps1 = (unsigned)(((4 + g) ^ (ln15 & 7)) << 4);
    const unsigned aBase = (unsigned)(wm * 128 + ln15) * 128;
    const unsigned bBase = (unsigned)(wn * 64 + ln15) * 128;

    f32x4 acc[8][4] = {};
    const int nkt = K >> 6;          // 16 K-tiles
    const int nit = nkt >> 1;        // 8 iterations

    stageA(0, 0); stageA(0, 1);
    stageB(0, 0); stageB(0, 1);
    stageB(1, 0); stageB(1, 1);
    asm volatile("s_waitcnt vmcnt(0)" ::: "memory");
    SBAR();

    for (int j = 0; j < nit; ++j) {
        const int t0 = 2 * j, t1 = 2 * j + 1;
        const bool more = (t0 + 2) < nkt;
        #pragma unroll
        for (int grp = 0; grp < 2; ++grp) {          // grp0: t0 (buf0), grp1: t1 (buf1)
            const char* Ab = (const char*)As[grp];
            const char* Bb = (const char*)Bs[grp];
            bf16x8 bfr[4][2];
            #pragma unroll
            for (int q = 0; q < 4; ++q) {
                if (q == 0) {
                    #pragma unroll
                    for (int nf = 0; nf < 4; ++nf) {
                        bfr[nf][0] = *reinterpret_cast<const bf16x8*>(Bb + bBase + nf * 2048 + ps0);
                        bfr[nf][1] = *reinterpret_cast<const bf16x8*>(Bb + bBase + nf * 2048 + ps1);
                    }
                }
                bf16x8 af0 = *reinterpret_cast<const bf16x8*>(Ab + aBase + (2 * q) * 2048 + ps0);
                bf16x8 af1 = *reinterpret_cast<const bf16x8*>(Ab + aBase + (2 * q) * 2048 + ps1);
                bf16x8 af2 = *reinterpret_cast<const bf16x8*>(Ab + aBase + (2 * q + 1) * 2048 + ps0);
                bf16x8 af3 = *reinterpret_cast<const bf16x8*>(Ab + aBase + (2 * q + 1) * 2048 + ps1);

                if (grp == 0) {
                    if (q == 0) stageA(t1, 0);
                    else if (q == 1) stageA(t1, 1);
                    else if (q == 2) { if (more) stageB(t0 + 2, 0); }
                    else {
                        if (more) { stageB(t0 + 2, 1);
                                    asm volatile("s_waitcnt vmcnt(4)" ::: "memory"); }
                        else      { asm volatile("s_waitcnt vmcnt(0)" ::: "memory"); }
                    }
                } else {
                    if (q == 0)      { if (more) stageA(t0 + 2, 0); }
                    else if (q == 1) { if (more) stageA(t0 + 2, 1); }
                    else if (q == 2) { if (more) stageB(t1 + 2, 0); }
                    else {
                        if (more) { stageB(t1 + 2, 1);
                                    asm volatile("s_waitcnt vmcnt(4)" ::: "memory"); }
                        else      { asm volatile("s_waitcnt vmcnt(0)" ::: "memory"); }
                    }
                }

                SBAR();
                asm volatile("s_waitcnt lgkmcnt(0)" ::: "memory");
                __builtin_amdgcn_s_setprio(1);
                #pragma unroll
                for (int nf = 0; nf < 4; ++nf) {
                    acc[2 * q][nf] = __builtin_amdgcn_mfma_f32_16x16x32_bf16(af0, bfr[nf][0], acc[2 * q][nf], 0, 0, 0);
                    acc[2 * q][nf] = __builtin_amdgcn_mfma_f32_16x16x32_bf16(af1, bfr[nf][1], acc[2 * q][nf], 0, 0, 0);
                    acc[2 * q + 1][nf] = __builtin_amdgcn_mfma_f32_16x16x32_bf16(af2, bfr[nf][0], acc[2 * q + 1][nf], 0, 0, 0);
                    acc[2 * q + 1][nf] = __builtin_amdgcn_mfma_f32_16x16x32_bf16(af3, bfr[nf][1], acc[2 * q + 1][nf], 0, 0, 0);
                }
                __builtin_amdgcn_s_setprio(0);
                SBAR();
            }
        }
    }

    // ---- fused epilogue ----
    const int sel = bn >> 2;                          // 0=Q, 1=K, 2=V
    unsigned short* tA = (unsigned short*)As;
    unsigned short* tB = (unsigned short*)Bs;
    if (sel == 2) {
        // V: bounce transposed tile through dead As/Bs, then coalesced store.
        #pragma unroll
        for (int mf = 0; mf < 8; ++mf) {
            int lrow = wm * 128 + mf * 16 + g * 4;
            #pragma unroll
            for (int nf = 0; nf < 4; ++nf) {
                int lcol = wn * 64 + nf * 16 + ln15;
                unsigned e = (unsigned)((lcol & 15) << 2);
                unsigned short* arr = (lcol < 128) ? tA : tB;
                ushort4 w;
                w.x = f2bf(acc[mf][nf][0]); w.y = f2bf(acc[mf][nf][1]);
                w.z = f2bf(acc[mf][nf][2]); w.w = f2bf(acc[mf][nf][3]);
                *reinterpret_cast<ushort4*>(
                    &arr[(unsigned)(lcol & 127) * 256 + ((unsigned)lrow ^ e)]) = w;
            }
        }
        __syncthreads();
        {
            int lcol = tid >> 1, sh = (tid & 1) << 7;   // 2 threads per (h,d) row
            unsigned e = (unsigned)((lcol & 15) << 2);
            const unsigned short* arr = (lcol < 128) ? tA : tB;
            unsigned base2 = (unsigned)(lcol & 127) * 256;
            int gcol = (bn & 3) * 256 + lcol;           // col within V section
            int h = gcol >> 6, d = gcol & 63;
            int srow_g = bm * 256;
            int b = srow_g >> 11;
            int sbase = (srow_g & 2047) + sh;
            unsigned short* ptr = Vtr + ((size_t)(b * NH + h) * 64 + d) * SEQ + sbase;
            #pragma unroll
            for (int k2 = 0; k2 < 32; ++k2) {
                ushort4 v = *reinterpret_cast<const ushort4*>(
                    &arr[base2 + (((unsigned)(sh + 4 * k2)) ^ e)]);
                *reinterpret_cast<ushort4*>(ptr + 4 * k2) = v;
            }
        }
    } else {
        // Q/K: RoPE in registers, bounce through dead As/Bs (natural
        // [row][col], 4-aligned XOR e=(r&7)<<2), then coalesced store:
        // each thread streams 2 complete (h,s)-rows = 256 B contiguous.
        const float sc = (sel == 0) ? QSCALE : 1.f;
        #pragma unroll
        for (int mf = 0; mf < 8; ++mf) {
            int lrow0 = wm * 128 + mf * 16 + g * 4;
            int s0 = (bm * 256 + lrow0) & 2047;
            #pragma unroll
            for (int nf = 0; nf < 4; ++nf) {
                int lcol = wn * 64 + nf * 16 + ln15;
                int d = lcol & 63;
                int i = d >> 1;
                #pragma unroll
                for (int j2 = 0; j2 < 4; ++j2) {
                    float v = acc[mf][nf][j2];
                    float p = __shfl_xor(v, 1);        // partner holds d^1
                    float2 cs = tab[((s0 + j2) << 5) + i];
                    float o = (d & 1) ? (v * cs.x + p * cs.y)
                                      : (v * cs.x - p * cs.y);
                    int r = lrow0 + j2;
                    unsigned e = (unsigned)((r & 7) << 2);
                    unsigned short* arr = (r < 128) ? tA : tB;
                    arr[(unsigned)(r & 127) * 256 + ((unsigned)lcol ^ e)] =
                        f2bf(o * sc);
                }
            }
        }
        __syncthreads();
        {
            unsigned short* dst = (sel == 0) ? Qh : Kh;
            int h_l = tid >> 7, t = tid & 127;          // head-local, row-pair
            int gcol = (bn & 3) * 256 + h_l * 64;
            int h = gcol >> 6;
            int srow_g = bm * 256;
            int b = srow_g >> 11;
            int sbase = (srow_g & 2047) + 2 * t;
            unsigned short* ptr = dst + ((size_t)(b * NH + h) * SEQ + sbase) * 64;
            #pragma unroll
            for (int rr = 0; rr < 2; ++rr) {
                int r = 2 * t + rr;
                unsigned e = (unsigned)((r & 7) << 2);
                const unsigned short* arr = (r < 128) ? tA : tB;
                unsigned base2 = (unsigned)(r & 127) * 256;
                #pragma unroll
                for (int k2 = 0; k2 < 16; ++k2) {
                    ushort4 v4 = *reinterpret_cast<const ushort4*>(
                        &arr[base2 + (((unsigned)(h_l * 64 + 4 * k2)) ^ e)]);
                    *reinterpret_cast<ushort4*>(ptr + rr * 64 + 4 * k2) = v4;
                }
            }
        }
    }
}

// ---------------- causal flash attention, KVBLK=64, 4 waves, uniform pairs ----
// r16's measured-best version, byte-identical.
__global__ __launch_bounds__(256) void attn_kernel(
    const unsigned short* __restrict__ Qh, const unsigned short* __restrict__ Kh,
    const unsigned short* __restrict__ Vt, unsigned short* __restrict__ Out) {
    __shared__ unsigned short Kb[2][64 * 64];   // [k][d], chunk-swizzled rows
    __shared__ unsigned short Vb[2][64 * 64];   // [d][k], chunk-swizzled rows
    __shared__ unsigned short Plds[4][16 * 72]; // per-wave P

    const int tid = threadIdx.x;
    const int wid = tid >> 6, lane = tid & 63;
    const int ln15 = lane & 15, g = lane >> 4;
    const int bid = blockIdx.x;
    const int bh = bid & 31;
    const int pb = bid >> 5;                    // 0..15 -> bands {pb, 31-pb}

    const unsigned short* Qp = Qh + (size_t)bh * SEQ * 64;
    const unsigned short* Kp = Kh + (size_t)bh * SEQ * 64;
    const unsigned short* Vp = Vt + (size_t)bh * 64 * SEQ;
    char* Pc = (char*)Plds[wid];

    // staging: 512 chunks x 16B per 64x64 tile; 256 threads x 2 chunks each
    const unsigned short* kSrc[2];
    const unsigned short* vSrc[2];
    #pragma unroll
    for (int p = 0; p < 2; ++p) {
        int c = tid + (p << 8);
        int row = c >> 3, slot = c & 7;
        kSrc[p] = Kp + (size_t)row * 64 + ((slot ^ (row & 7)) << 3);
        vSrc[p] = Vp + (size_t)row * SEQ + ((slot ^ (row & 7)) << 3);
    }
    auto stage = [&](int kb, int buf) {   // 4 gload_lds per thread
        #pragma unroll
        for (int p = 0; p < 2; ++p) {
            unsigned bb = (unsigned)((tid + (p << 8)) << 4);
            gload_lds16(kSrc[p] + (size_t)kb * 64, (char*)Kb[buf] + bb);
            gload_lds16(vSrc[p] + kb, (char*)Vb[buf] + bb);
        }
    };

    unsigned kOff[4][2], vOff[4][2];
    #pragma unroll
    for (int s = 0; s < 4; ++s) {
        int r = ln15 + 16 * s;
        kOff[s][0] = r * 128 + ((g ^ (r & 7)) << 4);
        kOff[s][1] = r * 128 + (((4 + g) ^ (r & 7)) << 4);
    }
    #pragma unroll
    for (int c = 0; c < 4; ++c) {
        int d = c * 16 + ln15;
        vOff[c][0] = d * 128 + ((g ^ (d & 7)) << 4);
        vOff[c][1] = d * 128 + (((4 + g) ^ (d & 7)) << 4);
    }
    const unsigned pW = (unsigned)(ln15 * 144 + 8 * g);   // + 32*s for quarter s
    const unsigned pR = (unsigned)(ln15 * 144 + 16 * g);  // + 64*h for half h

    const int b = bh >> 4, h = bh & 15;

    for (int bi = 0; bi < 2; ++bi) {
        const int bnd = bi ? (31 - pb) : pb;
        const int qb = bnd * 64 + wid * 16;
        const int nt = bnd + 1;                 // 64-wide k-tiles
        const int thr = qb + ln15 - 4 * g;      // allowed: kb + 16s + 4g + j <= qb + ln15

        bf16x8 aq0 = *reinterpret_cast<const bf16x8*>(Qp + (size_t)(qb + ln15) * 64 + g * 8);
        bf16x8 aq1 = *reinterpret_cast<const bf16x8*>(Qp + (size_t)(qb + ln15) * 64 + 32 + g * 8);

        f32x4 oacc[4] = {};
        float lsum = 0.f;

        stage(0, 0);   // band prologue

        for (int t = 0; t < nt; ++t) {
            const int kb = t << 6;
            const int cur = t & 1;
            if (t + 1 < nt) {
                stage((t + 1) << 6, cur ^ 1);
                asm volatile("s_waitcnt vmcnt(4)" ::: "memory");  // tile t's 4 done
            } else {
                asm volatile("s_waitcnt vmcnt(0)" ::: "memory");
            }
            __builtin_amdgcn_s_barrier();

            const char* K0 = (const char*)Kb[cur];
            const char* V0 = (const char*)Vb[cur];
            bf16x8 kf[8], bv[8];
            #pragma unroll
            for (int s = 0; s < 4; ++s) {
                kf[2 * s]     = *reinterpret_cast<const bf16x8*>(K0 + kOff[s][0]);
                kf[2 * s + 1] = *reinterpret_cast<const bf16x8*>(K0 + kOff[s][1]);
            }
            #pragma unroll
            for (int c = 0; c < 4; ++c) {
                bv[2 * c]     = *reinterpret_cast<const bf16x8*>(V0 + vOff[c][0]);
                bv[2 * c + 1] = *reinterpret_cast<const bf16x8*>(V0 + vOff[c][1]);
            }

            const f32x4 z = {};
            f32x4 sq[4];
            #pragma unroll
            for (int s = 0; s < 4; ++s) {
                sq[s] = __builtin_amdgcn_mfma_f32_16x16x32_bf16(kf[2 * s], aq0, z, 0, 0, 0);
                sq[s] = __builtin_amdgcn_mfma_f32_16x16x32_bf16(kf[2 * s + 1], aq1, sq[s], 0, 0, 0);
            }

            float pv[4][4];
            if (t == nt - 1) {      // boundary tile: causal mask
                #pragma unroll
                for (int s = 0; s < 4; ++s)
                    #pragma unroll
                    for (int j = 0; j < 4; ++j)
                        pv[s][j] = (j <= thr - kb - 16 * s) ? EXP2(sq[s][j]) : 0.f;
            } else {
                #pragma unroll
                for (int s = 0; s < 4; ++s)
                    #pragma unroll
                    for (int j = 0; j < 4; ++j)
                        pv[s][j] = EXP2(sq[s][j]);
            }
            #pragma unroll
            for (int s = 0; s < 4; ++s)
                lsum += (pv[s][0] + pv[s][1]) + (pv[s][2] + pv[s][3]);

            #pragma unroll
            for (int s = 0; s < 4; ++s) {
                ushort4 w;
                w.x = f2bf(pv[s][0]); w.y = f2bf(pv[s][1]);
                w.z = f2bf(pv[s][2]); w.w = f2bf(pv[s][3]);
                *reinterpret_cast<ushort4*>(Pc + pW + 32 * s) = w;
            }
            asm volatile("s_waitcnt lgkmcnt(0)" ::: "memory");
            bf16x8 ap0 = *reinterpret_cast<const bf16x8*>(Pc + pR);
            bf16x8 ap1 = *reinterpret_cast<const bf16x8*>(Pc + pR + 64);
            #pragma unroll
            for (int c = 0; c < 4; ++c) {
                oacc[c] = __builtin_amdgcn_mfma_f32_16x16x32_bf16(ap0, bv[2 * c], oacc[c], 0, 0, 0);
                oacc[c] = __builtin_amdgcn_mfma_f32_16x16x32_bf16(ap1, bv[2 * c + 1], oacc[c], 0, 0, 0);
            }
            asm volatile("s_waitcnt lgkmcnt(0)" ::: "memory");  // buf[cur] reads done
            __builtin_amdgcn_s_barrier();
        }

        // normalize + store this band
        float r = lsum;
        r += __shfl_xor(r, 16);
        r += __shfl_xor(r, 32);
        float linv = 1.f / r;
        float invj[4];
        #pragma unroll
        for (int j = 0; j < 4; ++j)
            invj[j] = __shfl(linv, 20 * g + j);   // lane with ln15 == 4g+j
        #pragma unroll
        for (int c = 0; c < 4; ++c)
            #pragma unroll
            for (int j = 0; j < 4; ++j) {
                int s = qb + g * 4 + j;
                Out[((size_t)(b * SEQ + s)) * DM + h * 64 + c * 16 + ln15] =
                    f2bf(oacc[c][j] * invj[j]);
            }
    }
}

extern "C" void kernel_launch(void* const* d_in, const int* in_sizes, int n_in,
                              void* d_out, int out_size, void* d_ws, size_t ws_size,
                              hipStream_t stream) {
    const float* x = (const float*)d_in[0];
    const int* pos = (const int*)d_in[1];
    const float* Wq = (const float*)d_in[2];
    const float* Wk = (const float*)d_in[3];
    const float* Wv = (const float*)d_in[4];
    const float* Wo = (const float*)d_in[5];
    float* out = (float*)d_out;

    char* ws = (char*)d_ws;
    const size_t MB = 1024 * 1024;
    unsigned short* xb   = (unsigned short*)(ws + 0 * MB);
    unsigned short* wqkv = (unsigned short*)(ws + 8 * MB);   // wq|wk|wv contiguous
    unsigned short* wob  = (unsigned short*)(ws + 14 * MB);
    float2*         tab  = (float2*)       (ws + 40 * MB);   // [2048][32]
    unsigned short* qh   = (unsigned short*)(ws + 41 * MB);
    unsigned short* kh   = (unsigned short*)(ws + 49 * MB);
    unsigned short* vtr  = (unsigned short*)(ws + 57 * MB);
    unsigned short* att  = (unsigned short*)(ws + 65 * MB);

    cvt_all<<<8448, 256, 0, stream>>>(x, Wq, Wk, Wv, Wo, pos, xb, wqkv, wob, tab);

    gemm256_bt<<<dim3(12, 16), 512, 0, stream>>>(xb, wqkv, qh, kh, vtr, tab, 1024);

    attn_kernel<<<512, 256, 0, stream>>>(qh, kh, vtr, att);

    gemm_bt<0><<<dim3(8, 32), 256, 0, stream>>>(att, wob, out, 4096, 1024, 1024);
}

// Round 24
// 110.291 us; speedup vs baseline: 1.0394x; 1.0394x over previous
//
#include <hip/hip_runtime.h>
#include <hip/hip_bf16.h>
#include <cstdint>
#include <cmath>

#define SEQ 2048
#define NH 16
#define DM 1024
#define BATCH 2

typedef short bf16x8 __attribute__((ext_vector_type(8)));
typedef float f32x4 __attribute__((ext_vector_type(4)));
typedef const void __attribute__((address_space(1)))* gas_t;
typedef void __attribute__((address_space(3)))* las_t;

#if __has_builtin(__builtin_amdgcn_exp2f)
#define EXP2(x) __builtin_amdgcn_exp2f(x)
#else
#define EXP2(x) __expf((x) * 0.6931471805599453f)
#endif

// Q prescale: (1/sqrt(64)) * log2(e) so scores are already in log2 domain
#define QSCALE 0.18033688011112042f

#define SBAR() asm volatile("s_barrier" ::: "memory")

static __device__ __forceinline__ unsigned short f2bf(float f) {
    union { __hip_bfloat16 h; unsigned short u; } cv;
    cv.h = __float2bfloat16(f);
    return cv.u;
}
static __device__ __forceinline__ float bf2f(unsigned short u) {
    union { unsigned short u; __hip_bfloat16 h; } cv;
    cv.u = u;
    return __bfloat162float(cv.h);
}

static __device__ __forceinline__ void gload_lds16(const void* g, void* l) {
    __builtin_amdgcn_global_load_lds(
        reinterpret_cast<gas_t>(reinterpret_cast<uintptr_t>(g)),
        reinterpret_cast<las_t>(reinterpret_cast<uintptr_t>(l)),
        16, 0, 0);
}

// ---------------- fp32 -> bf16 convert + RoPE table, one launch ----------
__global__ __launch_bounds__(256) void cvt_all(
    const float* __restrict__ x,  const float* __restrict__ wq,
    const float* __restrict__ wk, const float* __restrict__ wv,
    const float* __restrict__ wo, const int* __restrict__ pos,
    unsigned short* __restrict__ xb, unsigned short* __restrict__ wqkv,
    unsigned short* __restrict__ wob, float2* __restrict__ tab) {
    int blk = blockIdx.x;
    if (blk >= 8192) {                       // RoPE cos/sin table
        int idx = (blk - 8192) * 256 + threadIdx.x;   // s*32 + i
        int s = idx >> 5, i = idx & 31;
        float fpos = (float)pos[s];
        float freq = exp2f(-(float)i * (13.287712379549449f / 32.0f));
        float ang = fpos * freq, sn, cs;
        sincosf(ang, &sn, &cs);
        tab[idx] = make_float2(cs, sn);
        return;
    }
    const float* src; unsigned short* dst; int base;
    if (blk < 4096)      { src = x;  dst = xb;              base = blk; }
    else if (blk < 5120) { src = wq; dst = wqkv;            base = blk - 4096; }
    else if (blk < 6144) { src = wk; dst = wqkv + 1048576;  base = blk - 5120; }
    else if (blk < 7168) { src = wv; dst = wqkv + 2097152;  base = blk - 6144; }
    else                 { src = wo; dst = wob;             base = blk - 7168; }
    int i = base * 256 + threadIdx.x;
    float4 v = reinterpret_cast<const float4*>(src)[i];
    ushort4 o;
    o.x = f2bf(v.x); o.y = f2bf(v.y); o.z = f2bf(v.z); o.w = f2bf(v.w);
    reinterpret_cast<ushort4*>(dst)[i] = o;
}

// ---------------- 128x128 bf16 GEMM (out-proj): C = A * B^T ----------------
template<int OUT_BF16>
__global__ __launch_bounds__(256) void gemm_bt(
    const unsigned short* __restrict__ A,
    const unsigned short* __restrict__ B,
    void* __restrict__ C, int M, int N, int K) {
    __shared__ unsigned short As[128 * 32];
    __shared__ unsigned short Bs[128 * 32];
    const int tid = threadIdx.x;
    const int lane = tid & 63, wid = tid >> 6;
    const int wr = wid >> 1, wc = wid & 1;
    const int ln15 = lane & 15, kq = lane >> 4;
    const int bm = blockIdx.y, bn = blockIdx.x;

    f32x4 acc[4][4] = {};
    const int nk = K >> 5;
    for (int kt = 0; kt < nk; ++kt) {
        #pragma unroll
        for (int i = 0; i < 2; ++i) {
            int c = i * 256 + tid;
            int row = c >> 2, k8 = (c & 3) << 3;
            size_t gofsA = (size_t)(bm * 128 + row) * K + kt * 32 + k8;
            size_t gofsB = (size_t)(bn * 128 + row) * K + kt * 32 + k8;
            unsigned ldsoff_ = (unsigned)(i * 256 + wid * 64) * 16;  // wave-uniform
            gload_lds16(A + gofsA, (char*)As + ldsoff_);
            gload_lds16(B + gofsB, (char*)Bs + ldsoff_);
        }
        __syncthreads();
        bf16x8 af[4], bf[4];
        #pragma unroll
        for (int m = 0; m < 4; ++m)
            af[m] = *reinterpret_cast<const bf16x8*>(&As[(wr * 64 + m * 16 + ln15) * 32 + kq * 8]);
        #pragma unroll
        for (int n = 0; n < 4; ++n)
            bf[n] = *reinterpret_cast<const bf16x8*>(&Bs[(wc * 64 + n * 16 + ln15) * 32 + kq * 8]);
        #pragma unroll
        for (int m = 0; m < 4; ++m)
            #pragma unroll
            for (int n = 0; n < 4; ++n)
                acc[m][n] = __builtin_amdgcn_mfma_f32_16x16x32_bf16(af[m], bf[n], acc[m][n], 0, 0, 0);
        __syncthreads();
    }
    #pragma unroll
    for (int m = 0; m < 4; ++m) {
        #pragma unroll
        for (int n = 0; n < 4; ++n) {
            int col = bn * 128 + wc * 64 + n * 16 + ln15;
            #pragma unroll
            for (int j = 0; j < 4; ++j) {
                int row = bm * 128 + wr * 64 + m * 16 + kq * 4 + j;
                if constexpr (OUT_BF16 != 0)
                    ((unsigned short*)C)[(size_t)row * N + col] = f2bf(acc[m][n][j]);
                else
                    ((float*)C)[(size_t)row * N + col] = acc[m][n][j];
            }
        }
    }
}

// ---------------- 256x256 bf16 GEMM (qkv proj), 8-phase + fused epilogue -----
// r22 measured-best: V blocks bounce transposed tile through dead As/Bs LDS
// (coalesced Vtr store); Q/K RoPE stores direct.
__global__ __launch_bounds__(512) void gemm256_bt(
    const unsigned short* __restrict__ A,
    const unsigned short* __restrict__ B,
    unsigned short* __restrict__ Qh, unsigned short* __restrict__ Kh,
    unsigned short* __restrict__ Vtr, const float2* __restrict__ tab, int K) {
    __shared__ unsigned short As[2][256 * 64];
    __shared__ unsigned short Bs[2][256 * 64];
    const int tid = threadIdx.x;
    const int lane = tid & 63, wid = tid >> 6;
    const int wm = wid >> 2, wn = wid & 3;          // 2 x 4 waves
    const int ln15 = lane & 15, g = lane >> 4;
    const int bm = blockIdx.y, bn = blockIdx.x;

    const unsigned short* aSrc[4];
    const unsigned short* bSrc[4];
    #pragma unroll
    for (int p = 0; p < 4; ++p) {
        int c = tid + (p << 9);
        int row = c >> 3, slot = c & 7;
        aSrc[p] = A + (size_t)(bm * 256 + row) * K + ((slot ^ (row & 7)) << 3);
        bSrc[p] = B + (size_t)(bn * 256 + row) * K + ((slot ^ (row & 7)) << 3);
    }
    auto stageA = [&](int kt, int h) {   // one half-tile = 2 gload_lds / thread
        #pragma unroll
        for (int p = 2 * h; p < 2 * h + 2; ++p) {
            unsigned dst = (unsigned)(tid + (p << 9)) << 4;
            gload_lds16(aSrc[p] + kt * 64, (char*)As[kt & 1] + dst);
        }
    };
    auto stageB = [&](int kt, int h) {
        #pragma unroll
        for (int p = 2 * h; p < 2 * h + 2; ++p) {
            unsigned dst = (unsigned)(tid + (p << 9)) << 4;
            gload_lds16(bSrc[p] + kt * 64, (char*)Bs[kt & 1] + dst);
        }
    };

    const unsigned ps0 = (unsigned)((g ^ (ln15 & 7)) << 4);
    const unsigned ps1 = (unsigned)(((4 + g) ^ (ln15 & 7)) << 4);
    const unsigned aBase = (unsigned)(wm * 128 + ln15) * 128;
    const unsigned bBase = (unsigned)(wn * 64 + ln15) * 128;

    f32x4 acc[8][4] = {};
    const int nkt = K >> 6;          // 16 K-tiles
    const int nit = nkt >> 1;        // 8 iterations

    stageA(0, 0); stageA(0, 1);
    stageB(0, 0); stageB(0, 1);
    stageB(1, 0); stageB(1, 1);
    asm volatile("s_waitcnt vmcnt(0)" ::: "memory");
    SBAR();

    for (int j = 0; j < nit; ++j) {
        const int t0 = 2 * j, t1 = 2 * j + 1;
        const bool more = (t0 + 2) < nkt;
        #pragma unroll
        for (int grp = 0; grp < 2; ++grp) {          // grp0: t0 (buf0), grp1: t1 (buf1)
            const char* Ab = (const char*)As[grp];
            const char* Bb = (const char*)Bs[grp];
            bf16x8 bfr[4][2];
            #pragma unroll
            for (int q = 0; q < 4; ++q) {
                if (q == 0) {
                    #pragma unroll
                    for (int nf = 0; nf < 4; ++nf) {
                        bfr[nf][0] = *reinterpret_cast<const bf16x8*>(Bb + bBase + nf * 2048 + ps0);
                        bfr[nf][1] = *reinterpret_cast<const bf16x8*>(Bb + bBase + nf * 2048 + ps1);
                    }
                }
                bf16x8 af0 = *reinterpret_cast<const bf16x8*>(Ab + aBase + (2 * q) * 2048 + ps0);
                bf16x8 af1 = *reinterpret_cast<const bf16x8*>(Ab + aBase + (2 * q) * 2048 + ps1);
                bf16x8 af2 = *reinterpret_cast<const bf16x8*>(Ab + aBase + (2 * q + 1) * 2048 + ps0);
                bf16x8 af3 = *reinterpret_cast<const bf16x8*>(Ab + aBase + (2 * q + 1) * 2048 + ps1);

                if (grp == 0) {
                    if (q == 0) stageA(t1, 0);
                    else if (q == 1) stageA(t1, 1);
                    else if (q == 2) { if (more) stageB(t0 + 2, 0); }
                    else {
                        if (more) { stageB(t0 + 2, 1);
                                    asm volatile("s_waitcnt vmcnt(4)" ::: "memory"); }
                        else      { asm volatile("s_waitcnt vmcnt(0)" ::: "memory"); }
                    }
                } else {
                    if (q == 0)      { if (more) stageA(t0 + 2, 0); }
                    else if (q == 1) { if (more) stageA(t0 + 2, 1); }
                    else if (q == 2) { if (more) stageB(t1 + 2, 0); }
                    else {
                        if (more) { stageB(t1 + 2, 1);
                                    asm volatile("s_waitcnt vmcnt(4)" ::: "memory"); }
                        else      { asm volatile("s_waitcnt vmcnt(0)" ::: "memory"); }
                    }
                }

                SBAR();
                asm volatile("s_waitcnt lgkmcnt(0)" ::: "memory");
                __builtin_amdgcn_s_setprio(1);
                #pragma unroll
                for (int nf = 0; nf < 4; ++nf) {
                    acc[2 * q][nf] = __builtin_amdgcn_mfma_f32_16x16x32_bf16(af0, bfr[nf][0], acc[2 * q][nf], 0, 0, 0);
                    acc[2 * q][nf] = __builtin_amdgcn_mfma_f32_16x16x32_bf16(af1, bfr[nf][1], acc[2 * q][nf], 0, 0, 0);
                    acc[2 * q + 1][nf] = __builtin_amdgcn_mfma_f32_16x16x32_bf16(af2, bfr[nf][0], acc[2 * q + 1][nf], 0, 0, 0);
                    acc[2 * q + 1][nf] = __builtin_amdgcn_mfma_f32_16x16x32_bf16(af3, bfr[nf][1], acc[2 * q + 1][nf], 0, 0, 0);
                }
                __builtin_amdgcn_s_setprio(0);
                SBAR();
            }
        }
    }

    // ---- fused epilogue ----
    const int sel = bn >> 2;                          // 0=Q, 1=K, 2=V
    if (sel == 2) {
        // V: bounce transposed tile through dead As/Bs, then coalesced store.
        unsigned short* tA = (unsigned short*)As;
        unsigned short* tB = (unsigned short*)Bs;
        #pragma unroll
        for (int mf = 0; mf < 8; ++mf) {
            int lrow = wm * 128 + mf * 16 + g * 4;
            #pragma unroll
            for (int nf = 0; nf < 4; ++nf) {
                int lcol = wn * 64 + nf * 16 + ln15;
                unsigned e = (unsigned)((lcol & 15) << 2);
                unsigned short* arr = (lcol < 128) ? tA : tB;
                ushort4 w;
                w.x = f2bf(acc[mf][nf][0]); w.y = f2bf(acc[mf][nf][1]);
                w.z = f2bf(acc[mf][nf][2]); w.w = f2bf(acc[mf][nf][3]);
                *reinterpret_cast<ushort4*>(
                    &arr[(unsigned)(lcol & 127) * 256 + ((unsigned)lrow ^ e)]) = w;
            }
        }
        __syncthreads();
        {
            int lcol = tid >> 1, sh = (tid & 1) << 7;   // 2 threads per (h,d) row
            unsigned e = (unsigned)((lcol & 15) << 2);
            const unsigned short* arr = (lcol < 128) ? tA : tB;
            unsigned base2 = (unsigned)(lcol & 127) * 256;
            int gcol = (bn & 3) * 256 + lcol;           // col within V section
            int h = gcol >> 6, d = gcol & 63;
            int srow_g = bm * 256;
            int b = srow_g >> 11;
            int sbase = (srow_g & 2047) + sh;
            unsigned short* ptr = Vtr + ((size_t)(b * NH + h) * 64 + d) * SEQ + sbase;
            #pragma unroll
            for (int k2 = 0; k2 < 32; ++k2) {
                ushort4 v = *reinterpret_cast<const ushort4*>(
                    &arr[base2 + (((unsigned)(sh + 4 * k2)) ^ e)]);
                *reinterpret_cast<ushort4*>(ptr + 4 * k2) = v;
            }
        }
    } else {
        const int colBase = (bn & 3) * 256 + wn * 64;
        #pragma unroll
        for (int mf = 0; mf < 8; ++mf) {
            int row0 = bm * 256 + wm * 128 + mf * 16 + g * 4;
            int b = row0 >> 11, s0 = row0 & 2047;
            #pragma unroll
            for (int nf = 0; nf < 4; ++nf) {
                int col = colBase + nf * 16 + ln15;   // 0..1023
                int h = col >> 6, d = col & 63;
                unsigned short* dst = (sel == 0) ? Qh : Kh;
                const float sc = (sel == 0) ? QSCALE : 1.f;
                int i = d >> 1;
                #pragma unroll
                for (int j2 = 0; j2 < 4; ++j2) {
                    float v = acc[mf][nf][j2];
                    float p = __shfl_xor(v, 1);       // partner holds d^1
                    float2 cs = tab[((s0 + j2) << 5) + i];
                    float o = (d & 1) ? (v * cs.x + p * cs.y)
                                      : (v * cs.x - p * cs.y);
                    dst[(((size_t)(b * NH + h)) * SEQ + (s0 + j2)) * 64 + d] =
                        f2bf(o * sc);
                }
            }
        }
    }
}

// ---------------- causal flash attention, KVBLK=64, 4 waves, uniform pairs ----
// r16's measured-best version, byte-identical.
__global__ __launch_bounds__(256) void attn_kernel(
    const unsigned short* __restrict__ Qh, const unsigned short* __restrict__ Kh,
    const unsigned short* __restrict__ Vt, unsigned short* __restrict__ Out) {
    __shared__ unsigned short Kb[2][64 * 64];   // [k][d], chunk-swizzled rows
    __shared__ unsigned short Vb[2][64 * 64];   // [d][k], chunk-swizzled rows
    __shared__ unsigned short Plds[4][16 * 72]; // per-wave P

    const int tid = threadIdx.x;
    const int wid = tid >> 6, lane = tid & 63;
    const int ln15 = lane & 15, g = lane >> 4;
    const int bid = blockIdx.x;
    const int bh = bid & 31;
    const int pb = bid >> 5;                    // 0..15 -> bands {pb, 31-pb}

    const unsigned short* Qp = Qh + (size_t)bh * SEQ * 64;
    const unsigned short* Kp = Kh + (size_t)bh * SEQ * 64;
    const unsigned short* Vp = Vt + (size_t)bh * 64 * SEQ;
    char* Pc = (char*)Plds[wid];

    // staging: 512 chunks x 16B per 64x64 tile; 256 threads x 2 chunks each
    const unsigned short* kSrc[2];
    const unsigned short* vSrc[2];
    #pragma unroll
    for (int p = 0; p < 2; ++p) {
        int c = tid + (p << 8);
        int row = c >> 3, slot = c & 7;
        kSrc[p] = Kp + (size_t)row * 64 + ((slot ^ (row & 7)) << 3);
        vSrc[p] = Vp + (size_t)row * SEQ + ((slot ^ (row & 7)) << 3);
    }
    auto stage = [&](int kb, int buf) {   // 4 gload_lds per thread
        #pragma unroll
        for (int p = 0; p < 2; ++p) {
            unsigned bb = (unsigned)((tid + (p << 8)) << 4);
            gload_lds16(kSrc[p] + (size_t)kb * 64, (char*)Kb[buf] + bb);
            gload_lds16(vSrc[p] + kb, (char*)Vb[buf] + bb);
        }
    };

    unsigned kOff[4][2], vOff[4][2];
    #pragma unroll
    for (int s = 0; s < 4; ++s) {
        int r = ln15 + 16 * s;
        kOff[s][0] = r * 128 + ((g ^ (r & 7)) << 4);
        kOff[s][1] = r * 128 + (((4 + g) ^ (r & 7)) << 4);
    }
    #pragma unroll
    for (int c = 0; c < 4; ++c) {
        int d = c * 16 + ln15;
        vOff[c][0] = d * 128 + ((g ^ (d & 7)) << 4);
        vOff[c][1] = d * 128 + (((4 + g) ^ (d & 7)) << 4);
    }
    const unsigned pW = (unsigned)(ln15 * 144 + 8 * g);   // + 32*s for quarter s
    const unsigned pR = (unsigned)(ln15 * 144 + 16 * g);  // + 64*h for half h

    const int b = bh >> 4, h = bh & 15;

    for (int bi = 0; bi < 2; ++bi) {
        const int bnd = bi ? (31 - pb) : pb;
        const int qb = bnd * 64 + wid * 16;
        const int nt = bnd + 1;                 // 64-wide k-tiles
        const int thr = qb + ln15 - 4 * g;      // allowed: kb + 16s + 4g + j <= qb + ln15

        bf16x8 aq0 = *reinterpret_cast<const bf16x8*>(Qp + (size_t)(qb + ln15) * 64 + g * 8);
        bf16x8 aq1 = *reinterpret_cast<const bf16x8*>(Qp + (size_t)(qb + ln15) * 64 + 32 + g * 8);

        f32x4 oacc[4] = {};
        float lsum = 0.f;

        stage(0, 0);   // band prologue

        for (int t = 0; t < nt; ++t) {
            const int kb = t << 6;
            const int cur = t & 1;
            if (t + 1 < nt) {
                stage((t + 1) << 6, cur ^ 1);
                asm volatile("s_waitcnt vmcnt(4)" ::: "memory");  // tile t's 4 done
            } else {
                asm volatile("s_waitcnt vmcnt(0)" ::: "memory");
            }
            __builtin_amdgcn_s_barrier();

            const char* K0 = (const char*)Kb[cur];
            const char* V0 = (const char*)Vb[cur];
            bf16x8 kf[8], bv[8];
            #pragma unroll
            for (int s = 0; s < 4; ++s) {
                kf[2 * s]     = *reinterpret_cast<const bf16x8*>(K0 + kOff[s][0]);
                kf[2 * s + 1] = *reinterpret_cast<const bf16x8*>(K0 + kOff[s][1]);
            }
            #pragma unroll
            for (int c = 0; c < 4; ++c) {
                bv[2 * c]     = *reinterpret_cast<const bf16x8*>(V0 + vOff[c][0]);
                bv[2 * c + 1] = *reinterpret_cast<const bf16x8*>(V0 + vOff[c][1]);
            }

            const f32x4 z = {};
            f32x4 sq[4];
            #pragma unroll
            for (int s = 0; s < 4; ++s) {
                sq[s] = __builtin_amdgcn_mfma_f32_16x16x32_bf16(kf[2 * s], aq0, z, 0, 0, 0);
                sq[s] = __builtin_amdgcn_mfma_f32_16x16x32_bf16(kf[2 * s + 1], aq1, sq[s], 0, 0, 0);
            }

            float pv[4][4];
            if (t == nt - 1) {      // boundary tile: causal mask
                #pragma unroll
                for (int s = 0; s < 4; ++s)
                    #pragma unroll
                    for (int j = 0; j < 4; ++j)
                        pv[s][j] = (j <= thr - kb - 16 * s) ? EXP2(sq[s][j]) : 0.f;
            } else {
                #pragma unroll
                for (int s = 0; s < 4; ++s)
                    #pragma unroll
                    for (int j = 0; j < 4; ++j)
                        pv[s][j] = EXP2(sq[s][j]);
            }
            #pragma unroll
            for (int s = 0; s < 4; ++s)
                lsum += (pv[s][0] + pv[s][1]) + (pv[s][2] + pv[s][3]);

            #pragma unroll
            for (int s = 0; s < 4; ++s) {
                ushort4 w;
                w.x = f2bf(pv[s][0]); w.y = f2bf(pv[s][1]);
                w.z = f2bf(pv[s][2]); w.w = f2bf(pv[s][3]);
                *reinterpret_cast<ushort4*>(Pc + pW + 32 * s) = w;
            }
            asm volatile("s_waitcnt lgkmcnt(0)" ::: "memory");
            bf16x8 ap0 = *reinterpret_cast<const bf16x8*>(Pc + pR);
            bf16x8 ap1 = *reinterpret_cast<const bf16x8*>(Pc + pR + 64);
            #pragma unroll
            for (int c = 0; c < 4; ++c) {
                oacc[c] = __builtin_amdgcn_mfma_f32_16x16x32_bf16(ap0, bv[2 * c], oacc[c], 0, 0, 0);
                oacc[c] = __builtin_amdgcn_mfma_f32_16x16x32_bf16(ap1, bv[2 * c + 1], oacc[c], 0, 0, 0);
            }
            asm volatile("s_waitcnt lgkmcnt(0)" ::: "memory");  // buf[cur] reads done
            __builtin_amdgcn_s_barrier();
        }

        // normalize + store this band
        float r = lsum;
        r += __shfl_xor(r, 16);
        r += __shfl_xor(r, 32);
        float linv = 1.f / r;
        float invj[4];
        #pragma unroll
        for (int j = 0; j < 4; ++j)
            invj[j] = __shfl(linv, 20 * g + j);   // lane with ln15 == 4g+j
        #pragma unroll
        for (int c = 0; c < 4; ++c)
            #pragma unroll
            for (int j = 0; j < 4; ++j) {
                int s = qb + g * 4 + j;
                Out[((size_t)(b * SEQ + s)) * DM + h * 64 + c * 16 + ln15] =
                    f2bf(oacc[c][j] * invj[j]);
            }
    }
}

extern "C" void kernel_launch(void* const* d_in, const int* in_sizes, int n_in,
                              void* d_out, int out_size, void* d_ws, size_t ws_size,
                              hipStream_t stream) {
    const float* x = (const float*)d_in[0];
    const int* pos = (const int*)d_in[1];
    const float* Wq = (const float*)d_in[2];
    const float* Wk = (const float*)d_in[3];
    const float* Wv = (const float*)d_in[4];
    const float* Wo = (const float*)d_in[5];
    float* out = (float*)d_out;

    char* ws = (char*)d_ws;
    const size_t MB = 1024 * 1024;
    unsigned short* xb   = (unsigned short*)(ws + 0 * MB);
    unsigned short* wqkv = (unsigned short*)(ws + 8 * MB);   // wq|wk|wv contiguous
    unsigned short* wob  = (unsigned short*)(ws + 14 * MB);
    float2*         tab  = (float2*)       (ws + 40 * MB);   // [2048][32]
    unsigned short* qh   = (unsigned short*)(ws + 41 * MB);
    unsigned short* kh   = (unsigned short*)(ws + 49 * MB);
    unsigned short* vtr  = (unsigned short*)(ws + 57 * MB);
    unsigned short* att  = (unsigned short*)(ws + 65 * MB);

    cvt_all<<<8448, 256, 0, stream>>>(x, Wq, Wk, Wv, Wo, pos, xb, wqkv, wob, tab);

    gemm256_bt<<<dim3(12, 16), 512, 0, stream>>>(xb, wqkv, qh, kh, vtr, tab, 1024);

    attn_kernel<<<512, 256, 0, stream>>>(qh, kh, vtr, att);

    gemm_bt<0><<<dim3(8, 32), 256, 0, stream>>>(att, wob, out, 4096, 1024, 1024);
}